// Round 7
// baseline (203.821 us; speedup 1.0000x reference)
//
#include <hip/hip_runtime.h>
#include <hip/hip_bf16.h>

typedef __attribute__((ext_vector_type(8))) short bf16x8;
typedef __attribute__((ext_vector_type(4))) float f32x4;

#define KDIM 2048
#define BK 64
#define NKT (KDIM / BK)

__device__ __forceinline__ unsigned short f2bf(float f) {
  union { float fv; unsigned int u; } c; c.fv = f;
  unsigned int u = c.u;
  unsigned int r = (u + 0x7FFFu + ((u >> 16) & 1u)) >> 16;
  return (unsigned short)r;
}

__device__ __forceinline__ void gload_lds16(const unsigned short* g, unsigned short* l) {
  auto gp = reinterpret_cast<const __attribute__((address_space(1))) unsigned int*>(
      reinterpret_cast<uintptr_t>(g));
  auto lp = reinterpret_cast<__attribute__((address_space(3))) unsigned int*>(
      reinterpret_cast<uintptr_t>(l));
  __builtin_amdgcn_global_load_lds(gp, lp, 16, 0, 0);
}

__device__ __forceinline__ float sigm(float z) { return 1.0f / (1.0f + __expf(-z)); }
__device__ __forceinline__ float tanh_fast(float z) { return 1.0f - 2.0f / (__expf(2.0f * z) + 1.0f); }

// Build hx = [x | h] as bf16 [4096][2048]
__global__ void pack_hx_kernel(const float* __restrict__ x, const float* __restrict__ h,
                               unsigned short* __restrict__ hx) {
  int idx = (blockIdx.x * blockDim.x + threadIdx.x) * 4;
  int row = idx >> 11;
  int col = idx & 2047;
  const float* src = (col < 1024) ? (x + (size_t)row * 1024 + col)
                                  : (h + (size_t)row * 1024 + (col - 1024));
  float4 v = *reinterpret_cast<const float4*>(src);
  ushort4 o = make_ushort4(f2bf(v.x), f2bf(v.y), f2bf(v.z), f2bf(v.w));
  *reinterpret_cast<ushort4*>(hx + idx) = o;
}

// All four W [2048][1024] f32 -> Wt [4][1024][2048] bf16 in one launch (z = gate)
__global__ void transpose_w4_kernel(const float* __restrict__ W0, const float* __restrict__ W1,
                                    const float* __restrict__ W2, const float* __restrict__ W3,
                                    unsigned short* __restrict__ Wt) {
  __shared__ float tile[32][33];
  const int g = blockIdx.z;
  const float* W = (g == 0) ? W0 : (g == 1) ? W1 : (g == 2) ? W2 : W3;
  unsigned short* T = Wt + (size_t)g * 1024 * 2048;
  int n0 = blockIdx.x * 32;
  int k0 = blockIdx.y * 32;
  int tx = threadIdx.x;
  int ty = threadIdx.y;
#pragma unroll
  for (int i = 0; i < 4; ++i)
    tile[ty + 8 * i][tx] = W[(size_t)(k0 + ty + 8 * i) * 1024 + (n0 + tx)];
  __syncthreads();
#pragma unroll
  for (int i = 0; i < 4; ++i)
    T[(size_t)(n0 + ty + 8 * i) * 2048 + (k0 + tx)] = f2bf(tile[tx][ty + 8 * i]);
}

// ---- inline-asm LDS read (invisible to compiler's waitcnt insertion) ----
#define DSR(dst, base, imm) \
  asm volatile("ds_read_b128 %0, %1 offset:%c2" : "=v"(dst) : "v"(base), "i"(imm))

#define LGKM(N)                                                   \
  do {                                                            \
    asm volatile("s_waitcnt lgkmcnt(" #N ")" ::: "memory");       \
    __builtin_amdgcn_sched_barrier(0);                            \
  } while (0)

#define VMC(N)                                                    \
  do {                                                            \
    asm volatile("s_waitcnt vmcnt(" #N ")" ::: "memory");         \
    __builtin_amdgcn_sched_barrier(0);                            \
  } while (0)

#define KEEPV(x) asm volatile("" ::"v"(x))

#define GMF(G, S)                                                                   \
  __builtin_amdgcn_s_setprio(1);                                                    \
  _Pragma("unroll") for (int m = 0; m < 4; ++m)                                     \
      _Pragma("unroll") for (int n = 0; n < 2; ++n) {                               \
    acc[G][m][n] = __builtin_amdgcn_mfma_f32_16x16x32_bf16(aF[m][0], S[n][0],       \
                                                           acc[G][m][n], 0, 0, 0); \
    acc[G][m][n] = __builtin_amdgcn_mfma_f32_16x16x32_bf16(aF[m][1], S[n][1],       \
                                                           acc[G][m][n], 0, 0, 0); \
  }                                                                                 \
  __builtin_amdgcn_s_setprio(0);

#define STAGE(P)                                                        \
  {                                                                     \
    _Pragma("unroll") for (int i = 0; i < 4; ++i)                       \
        gload_lds16(srcA[i], &lA[P][dA[i]]);                            \
    _Pragma("unroll") for (int g = 0; g < 4; ++g)                       \
        gload_lds16(srcB[g], &lB[P][dB[g]]);                            \
    _Pragma("unroll") for (int i = 0; i < 4; ++i) srcA[i] += BK;        \
    _Pragma("unroll") for (int g = 0; g < 4; ++g) srcB[g] += BK;        \
  }

#define TILE(P, T)                                                      \
  {                                                                     \
    bf16x8 aF[4][2], S0[2][2], S1[2][2], S2[2][2];                      \
    _Pragma("unroll") for (int m = 0; m < 4; ++m) {                     \
      DSR(aF[m][0], a_base0, (P)*32768 + m * 2048);                     \
      DSR(aF[m][1], a_base1, (P)*32768 + m * 2048);                     \
    }                                                                   \
    _Pragma("unroll") for (int n = 0; n < 2; ++n) {                     \
      DSR(S0[n][0], b_base0, (P)*32768 + 0 * 8192 + n * 2048);          \
      DSR(S0[n][1], b_base1, (P)*32768 + 0 * 8192 + n * 2048);          \
    }                                                                   \
    _Pragma("unroll") for (int n = 0; n < 2; ++n) {                     \
      DSR(S1[n][0], b_base0, (P)*32768 + 1 * 8192 + n * 2048);          \
      DSR(S1[n][1], b_base1, (P)*32768 + 1 * 8192 + n * 2048);          \
    }                                                                   \
    LGKM(4);                                                            \
    GMF(0, S0)                                                          \
    _Pragma("unroll") for (int n = 0; n < 2; ++n) {                     \
      DSR(S2[n][0], b_base0, (P)*32768 + 2 * 8192 + n * 2048);          \
      DSR(S2[n][1], b_base1, (P)*32768 + 2 * 8192 + n * 2048);          \
    }                                                                   \
    LGKM(4);                                                            \
    GMF(1, S1)                                                          \
    _Pragma("unroll") for (int n = 0; n < 2; ++n) {                     \
      DSR(S0[n][0], b_base0, (P)*32768 + 3 * 8192 + n * 2048);          \
      DSR(S0[n][1], b_base1, (P)*32768 + 3 * 8192 + n * 2048);          \
    }                                                                   \
    LGKM(4);                                                            \
    GMF(2, S2)                                                          \
    LGKM(0);                                                            \
    GMF(3, S0)                                                          \
    __builtin_amdgcn_s_barrier();                                       \
    __builtin_amdgcn_sched_barrier(0);                                  \
    if ((T) < NKT - 2) STAGE(P)                                         \
    if ((T) < NKT - 2) { VMC(8); } else { VMC(0); }                     \
    __builtin_amdgcn_s_barrier();                                       \
    __builtin_amdgcn_sched_barrier(0);                                  \
  }

// LDS+stage+barrier structure, MFMA removed (fragments kept live).
#define TILE_LDS(P, T)                                                  \
  {                                                                     \
    bf16x8 aF[4][2], S0[2][2], S1[2][2], S2[2][2];                      \
    _Pragma("unroll") for (int m = 0; m < 4; ++m) {                     \
      DSR(aF[m][0], a_base0, (P)*32768 + m * 2048);                     \
      DSR(aF[m][1], a_base1, (P)*32768 + m * 2048);                     \
    }                                                                   \
    _Pragma("unroll") for (int n = 0; n < 2; ++n) {                     \
      DSR(S0[n][0], b_base0, (P)*32768 + 0 * 8192 + n * 2048);          \
      DSR(S0[n][1], b_base1, (P)*32768 + 0 * 8192 + n * 2048);          \
    }                                                                   \
    _Pragma("unroll") for (int n = 0; n < 2; ++n) {                     \
      DSR(S1[n][0], b_base0, (P)*32768 + 1 * 8192 + n * 2048);          \
      DSR(S1[n][1], b_base1, (P)*32768 + 1 * 8192 + n * 2048);          \
    }                                                                   \
    LGKM(4);                                                            \
    _Pragma("unroll") for (int m = 0; m < 4; ++m) { KEEPV(aF[m][0]); KEEPV(aF[m][1]); } \
    _Pragma("unroll") for (int n = 0; n < 2; ++n) { KEEPV(S0[n][0]); KEEPV(S0[n][1]); } \
    _Pragma("unroll") for (int n = 0; n < 2; ++n) {                     \
      DSR(S2[n][0], b_base0, (P)*32768 + 2 * 8192 + n * 2048);          \
      DSR(S2[n][1], b_base1, (P)*32768 + 2 * 8192 + n * 2048);          \
    }                                                                   \
    LGKM(4);                                                            \
    _Pragma("unroll") for (int n = 0; n < 2; ++n) { KEEPV(S1[n][0]); KEEPV(S1[n][1]); } \
    _Pragma("unroll") for (int n = 0; n < 2; ++n) {                     \
      DSR(S0[n][0], b_base0, (P)*32768 + 3 * 8192 + n * 2048);          \
      DSR(S0[n][1], b_base1, (P)*32768 + 3 * 8192 + n * 2048);          \
    }                                                                   \
    LGKM(4);                                                            \
    _Pragma("unroll") for (int n = 0; n < 2; ++n) { KEEPV(S2[n][0]); KEEPV(S2[n][1]); } \
    LGKM(0);                                                            \
    _Pragma("unroll") for (int n = 0; n < 2; ++n) { KEEPV(S0[n][0]); KEEPV(S0[n][1]); } \
    __builtin_amdgcn_s_barrier();                                       \
    __builtin_amdgcn_sched_barrier(0);                                  \
    if ((T) < NKT - 2) STAGE(P)                                         \
    if ((T) < NKT - 2) { VMC(8); } else { VMC(0); }                     \
    __builtin_amdgcn_s_barrier();                                       \
    __builtin_amdgcn_sched_barrier(0);                                  \
  }

// ===================== real kernel (unchanged from R6) =====================
__global__ __launch_bounds__(512, 2) void lstm_fused_kernel(
    const unsigned short* __restrict__ hx,
    const unsigned short* __restrict__ wtb,
    const float* __restrict__ bias_f,
    const float* __restrict__ bias_i,
    const float* __restrict__ bias_s,
    const float* __restrict__ bias_p,
    const float* __restrict__ c_in,
    float* __restrict__ out) {
  __shared__ unsigned short lA[2][256 * BK];
  __shared__ unsigned short lB[2][4 * 64 * BK];

  const int tid  = threadIdx.x;
  const int lane = tid & 63;
  const int wid  = tid >> 6;
  const int wr   = wid >> 1;
  const int wc   = wid & 1;
  const int lg   = lane >> 4;
  const int ll   = lane & 15;

  const int wg   = (blockIdx.x & 7) * 32 + (blockIdx.x >> 3);
  const int brow = wg >> 4;
  const int bcol = wg & 15;

  const unsigned short* srcA[4];
  unsigned int dA[4];
#pragma unroll
  for (int i = 0; i < 4; ++i) {
    int s = i * 512 + tid;
    int r = s >> 3, sch = s & 7;
    int ch = sch ^ (r & 7);
    srcA[i] = hx + (size_t)(brow * 256 + r) * KDIM + ch * 8;
    dA[i] = s * 8;
  }
  const unsigned short* srcB[4];
  unsigned int dB[4];
  {
    int r = tid >> 3, sch = tid & 7;
    int ch = sch ^ (r & 7);
#pragma unroll
    for (int g = 0; g < 4; ++g) {
      srcB[g] = wtb + (size_t)g * 1024 * 2048 + (size_t)(bcol * 64 + r) * KDIM + ch * 8;
      dB[g] = g * 4096 + tid * 8;
    }
  }

  const unsigned ldsA = (unsigned)(uintptr_t)(&lA[0][0]);
  const unsigned ldsB = (unsigned)(uintptr_t)(&lB[0][0]);
  const int ch0 = lg ^ (ll & 7);
  const int ch1 = ch0 ^ 4;
  const unsigned a_base0 = ldsA + (unsigned)(((wr * 64 + ll) * 64 + ch0 * 8) * 2);
  const unsigned a_base1 = ldsA + (unsigned)(((wr * 64 + ll) * 64 + ch1 * 8) * 2);
  const unsigned b_base0 = ldsB + (unsigned)(((wc * 32 + ll) * 64 + ch0 * 8) * 2);
  const unsigned b_base1 = ldsB + (unsigned)(((wc * 32 + ll) * 64 + ch1 * 8) * 2);

  f32x4 acc[4][4][2];
#pragma unroll
  for (int g = 0; g < 4; ++g)
#pragma unroll
    for (int m = 0; m < 4; ++m)
#pragma unroll
      for (int n = 0; n < 2; ++n)
        acc[g][m][n] = (f32x4)(0.0f);

  STAGE(0)
  STAGE(1)
  VMC(8);
  __builtin_amdgcn_s_barrier();
  __builtin_amdgcn_sched_barrier(0);

  for (int t = 0; t < NKT; t += 2) {
    TILE(0, t)
    TILE(1, t + 1)
  }

  const int row0 = brow * 256 + wr * 64;
  const int col0 = bcol * 64 + wc * 32;
  float bv[4][2];
#pragma unroll
  for (int n = 0; n < 2; ++n) {
    int col = col0 + n * 16 + ll;
    bv[0][n] = bias_f[col];
    bv[1][n] = bias_i[col];
    bv[2][n] = bias_s[col];
    bv[3][n] = bias_p[col];
  }
#pragma unroll
  for (int m = 0; m < 4; ++m)
#pragma unroll
    for (int n = 0; n < 2; ++n)
#pragma unroll
      for (int j = 0; j < 4; ++j) {
        int row = row0 + m * 16 + lg * 4 + j;
        int col = col0 + n * 16 + ll;
        float zf = acc[0][m][n][j] + bv[0][n];
        float zi = acc[1][m][n][j] + bv[1][n];
        float zs = acc[2][m][n][j] + bv[2][n];
        float zp = acc[3][m][n][j] + bv[3][n];
        float fg = sigm(zf);
        float ig = sigm(zi);
        float sg = sigm(zs);
        float pg = tanh_fast(zp);
        float cn = c_in[(size_t)row * 1024 + col] * fg + ig * pg;
        out[(size_t)row * 1024 + col] = tanh_fast(cn) * sg;
      }
}

// ===================== probe 1: MFMA stream only, 2x passes =====================
__global__ __launch_bounds__(512, 2) void probe_mfma_x2(float* __restrict__ scr) {
  __shared__ unsigned short lA[2][256 * BK];
  __shared__ unsigned short lB[2][4 * 64 * BK];
  const int tid = threadIdx.x;
  lA[0][tid] = (unsigned short)tid;   // keep LDS allocated (occupancy parity)
  lB[0][tid] = (unsigned short)tid;

  f32x4 acc[4][4][2];
#pragma unroll
  for (int g = 0; g < 4; ++g)
#pragma unroll
    for (int m = 0; m < 4; ++m)
#pragma unroll
      for (int n = 0; n < 2; ++n)
        acc[g][m][n] = (f32x4)(0.0f);

  bf16x8 one;
#pragma unroll
  for (int j = 0; j < 8; ++j) one[j] = (short)0x3F80;
  bf16x8 aF[4][2], S[2][2];
#pragma unroll
  for (int m = 0; m < 4; ++m) { aF[m][0] = one; aF[m][1] = one; }
#pragma unroll
  for (int n = 0; n < 2; ++n) { S[n][0] = one; S[n][1] = one; }

  for (int rep = 0; rep < 2; ++rep)
    for (int t = 0; t < NKT; ++t) {
      GMF(0, S)
      GMF(1, S)
      GMF(2, S)
      GMF(3, S)
    }

  float s = 0.0f;
#pragma unroll
  for (int g = 0; g < 4; ++g)
#pragma unroll
    for (int m = 0; m < 4; ++m)
#pragma unroll
      for (int n = 0; n < 2; ++n)
        s += acc[g][m][n][0];
  s += (float)lA[0][(tid + 1) & 511] + (float)lB[0][(tid + 1) & 511];
  scr[blockIdx.x * 512 + tid] = s;
}

// ===================== probe 2: LDS reads + staging + barriers, 2x passes =====================
__global__ __launch_bounds__(512, 2) void probe_ldsstage_x2(
    const unsigned short* __restrict__ hx,
    const unsigned short* __restrict__ wtb,
    float* __restrict__ scr) {
  __shared__ unsigned short lA[2][256 * BK];
  __shared__ unsigned short lB[2][4 * 64 * BK];

  const int tid  = threadIdx.x;
  const int lane = tid & 63;
  const int wid  = tid >> 6;
  const int wr   = wid >> 1;
  const int wc   = wid & 1;
  const int lg   = lane >> 4;
  const int ll   = lane & 15;

  const int wg   = (blockIdx.x & 7) * 32 + (blockIdx.x >> 3);
  const int brow = wg >> 4;
  const int bcol = wg & 15;

  const unsigned short* srcA0[4];
  unsigned int dA[4];
#pragma unroll
  for (int i = 0; i < 4; ++i) {
    int s = i * 512 + tid;
    int r = s >> 3, sch = s & 7;
    int ch = sch ^ (r & 7);
    srcA0[i] = hx + (size_t)(brow * 256 + r) * KDIM + ch * 8;
    dA[i] = s * 8;
  }
  const unsigned short* srcB0[4];
  unsigned int dB[4];
  {
    int r = tid >> 3, sch = tid & 7;
    int ch = sch ^ (r & 7);
#pragma unroll
    for (int g = 0; g < 4; ++g) {
      srcB0[g] = wtb + (size_t)g * 1024 * 2048 + (size_t)(bcol * 64 + r) * KDIM + ch * 8;
      dB[g] = g * 4096 + tid * 8;
    }
  }

  const unsigned ldsA = (unsigned)(uintptr_t)(&lA[0][0]);
  const unsigned ldsB = (unsigned)(uintptr_t)(&lB[0][0]);
  const int ch0 = lg ^ (ll & 7);
  const int ch1 = ch0 ^ 4;
  const unsigned a_base0 = ldsA + (unsigned)(((wr * 64 + ll) * 64 + ch0 * 8) * 2);
  const unsigned a_base1 = ldsA + (unsigned)(((wr * 64 + ll) * 64 + ch1 * 8) * 2);
  const unsigned b_base0 = ldsB + (unsigned)(((wc * 32 + ll) * 64 + ch0 * 8) * 2);
  const unsigned b_base1 = ldsB + (unsigned)(((wc * 32 + ll) * 64 + ch1 * 8) * 2);

  for (int rep = 0; rep < 2; ++rep) {
    const unsigned short* srcA[4];
    const unsigned short* srcB[4];
#pragma unroll
    for (int i = 0; i < 4; ++i) srcA[i] = srcA0[i];
#pragma unroll
    for (int g = 0; g < 4; ++g) srcB[g] = srcB0[g];

    STAGE(0)
    STAGE(1)
    VMC(8);
    __builtin_amdgcn_s_barrier();
    __builtin_amdgcn_sched_barrier(0);

    for (int t = 0; t < NKT; t += 2) {
      TILE_LDS(0, t)
      TILE_LDS(1, t + 1)
    }
  }

  scr[blockIdx.x * 512 + tid] = (float)lA[0][tid] + (float)lB[0][tid];
}

extern "C" void kernel_launch(void* const* d_in, const int* in_sizes, int n_in,
                              void* d_out, int out_size, void* d_ws, size_t ws_size,
                              hipStream_t stream) {
  const float* x  = (const float*)d_in[0];
  const float* h  = (const float*)d_in[1];
  const float* c  = (const float*)d_in[2];
  const float* Wf = (const float*)d_in[3];
  const float* bf = (const float*)d_in[4];
  const float* Wi = (const float*)d_in[5];
  const float* bi = (const float*)d_in[6];
  const float* Ws = (const float*)d_in[7];
  const float* bs = (const float*)d_in[8];
  const float* Wp = (const float*)d_in[9];
  const float* bp = (const float*)d_in[10];
  float* out = (float*)d_out;

  unsigned short* ws = (unsigned short*)d_ws;
  unsigned short* hx  = ws;                        // 16 MB (rebuilt every replay)
  unsigned short* wtb = ws + (size_t)4096 * 2048;  // 16 MB (rebuilt every replay)
  float* scr = (float*)d_ws;                       // probe sink (aliases hx; rebuilt)

  pack_hx_kernel<<<(4096 * 2048 / 4) / 256, 256, 0, stream>>>(x, h, hx);

  dim3 tb(32, 8);
  dim3 tg(1024 / 32, 2048 / 32, 4);
  transpose_w4_kernel<<<tg, tb, 0, stream>>>(Wf, Wi, Ws, Wp, wtb);

  lstm_fused_kernel<<<256, 512, 0, stream>>>(hx, wtb, bf, bi, bs, bp, c, out);

  // --- timing probes (write scratch only; hx is rebuilt before next use) ---
  probe_mfma_x2<<<256, 512, 0, stream>>>(scr);
  probe_ldsstage_x2<<<256, 512, 0, stream>>>(hx, wtb, scr);
}

// Round 8
// 87.042 us; speedup vs baseline: 2.3416x; 2.3416x over previous
//
#include <hip/hip_runtime.h>
#include <hip/hip_bf16.h>

typedef __attribute__((ext_vector_type(8))) short bf16x8;
typedef __attribute__((ext_vector_type(4))) float f32x4;

#define KDIM 2048
#define BK 64
#define NKT (KDIM / BK)

__device__ __forceinline__ unsigned short f2bf(float f) {
  union { float fv; unsigned int u; } c; c.fv = f;
  unsigned int u = c.u;
  unsigned int r = (u + 0x7FFFu + ((u >> 16) & 1u)) >> 16;
  return (unsigned short)r;
}

__device__ __forceinline__ void gload_lds16(const unsigned short* g, unsigned short* l) {
  auto gp = reinterpret_cast<const __attribute__((address_space(1))) unsigned int*>(
      reinterpret_cast<uintptr_t>(g));
  auto lp = reinterpret_cast<__attribute__((address_space(3))) unsigned int*>(
      reinterpret_cast<uintptr_t>(l));
  __builtin_amdgcn_global_load_lds(gp, lp, 16, 0, 0);
}

__device__ __forceinline__ float sigm(float z) { return 1.0f / (1.0f + __expf(-z)); }
__device__ __forceinline__ float tanh_fast(float z) { return 1.0f - 2.0f / (__expf(2.0f * z) + 1.0f); }

// Build hx = [x | h] as bf16 [4096][2048]
__global__ void pack_hx_kernel(const float* __restrict__ x, const float* __restrict__ h,
                               unsigned short* __restrict__ hx) {
  int idx = (blockIdx.x * blockDim.x + threadIdx.x) * 4;
  int row = idx >> 11;
  int col = idx & 2047;
  const float* src = (col < 1024) ? (x + (size_t)row * 1024 + col)
                                  : (h + (size_t)row * 1024 + (col - 1024));
  float4 v = *reinterpret_cast<const float4*>(src);
  ushort4 o = make_ushort4(f2bf(v.x), f2bf(v.y), f2bf(v.z), f2bf(v.w));
  *reinterpret_cast<ushort4*>(hx + idx) = o;
}

// All four W [2048][1024] f32 -> Wt [4][1024][2048] bf16 in one launch (z = gate)
__global__ void transpose_w4_kernel(const float* __restrict__ W0, const float* __restrict__ W1,
                                    const float* __restrict__ W2, const float* __restrict__ W3,
                                    unsigned short* __restrict__ Wt) {
  __shared__ float tile[32][33];
  const int g = blockIdx.z;
  const float* W = (g == 0) ? W0 : (g == 1) ? W1 : (g == 2) ? W2 : W3;
  unsigned short* T = Wt + (size_t)g * 1024 * 2048;
  int n0 = blockIdx.x * 32;
  int k0 = blockIdx.y * 32;
  int tx = threadIdx.x;
  int ty = threadIdx.y;
#pragma unroll
  for (int i = 0; i < 4; ++i)
    tile[ty + 8 * i][tx] = W[(size_t)(k0 + ty + 8 * i) * 1024 + (n0 + tx)];
  __syncthreads();
#pragma unroll
  for (int i = 0; i < 4; ++i)
    T[(size_t)(n0 + ty + 8 * i) * 2048 + (k0 + tx)] = f2bf(tile[tx][ty + 8 * i]);
}

// ---- sync primitives: asm barrier (no compiler auto-drain), counted waits, NO sched pins ----
#define BAR  asm volatile("s_barrier" ::: "memory")
#define LGKM0 asm volatile("s_waitcnt lgkmcnt(0)" ::: "memory")
#define VMC(N) asm volatile("s_waitcnt vmcnt(" #N ")" ::: "memory")

#define READ_AF()                                                               \
  {                                                                             \
    _Pragma("unroll") for (int m = 0; m < 4; ++m)                               \
        _Pragma("unroll") for (int ks = 0; ks < 2; ++ks)                        \
            aF[m][ks] = *reinterpret_cast<const bf16x8*>(Ab + aoff[m][ks]);     \
  }

#define READ_BF(G)                                                              \
  {                                                                             \
    _Pragma("unroll") for (int n = 0; n < 2; ++n)                               \
        _Pragma("unroll") for (int ks = 0; ks < 2; ++ks)                        \
            bF[n][ks] = *reinterpret_cast<const bf16x8*>(Bb + (G)*4096 + boff[n][ks]); \
  }

#define MFMA_GATE(G)                                                            \
  __builtin_amdgcn_s_setprio(1);                                                \
  _Pragma("unroll") for (int m = 0; m < 4; ++m)                                 \
      _Pragma("unroll") for (int n = 0; n < 2; ++n)                             \
          _Pragma("unroll") for (int ks = 0; ks < 2; ++ks)                      \
              acc[G][m][n] = __builtin_amdgcn_mfma_f32_16x16x32_bf16(           \
                  aF[m][ks], bF[n][ks], acc[G][m][n], 0, 0, 0);                 \
  __builtin_amdgcn_s_setprio(0);

// Fused 4-gate GEMM + LSTM epilogue. T3+T4 proper: loads live ACROSS barriers.
// Grid: 256 blocks (1/CU), 512 threads (8 waves, 4M x 2N; wave = 64 rows x 32 cols x 4 gates).
__global__ __launch_bounds__(512, 2) void lstm_fused_kernel(
    const unsigned short* __restrict__ hx,
    const unsigned short* __restrict__ wtb,
    const float* __restrict__ bias_f,
    const float* __restrict__ bias_i,
    const float* __restrict__ bias_s,
    const float* __restrict__ bias_p,
    const float* __restrict__ c_in,
    float* __restrict__ out) {
  __shared__ unsigned short lA[2][256 * BK];      // 2 x 32 KB
  __shared__ unsigned short lB[2][4 * 64 * BK];   // 2 x 32 KB

  const int tid  = threadIdx.x;
  const int lane = tid & 63;
  const int wid  = tid >> 6;
  const int wr   = wid >> 1;  // 0..3 : 64-row slice
  const int wc   = wid & 1;   // 0..1 : 32-col slice
  const int lg   = lane >> 4;
  const int ll   = lane & 15;

  // bijective XCD swizzle (256 % 8 == 0)
  const int wg   = (blockIdx.x & 7) * 32 + (blockIdx.x >> 3);
  const int brow = wg >> 4;  // 0..15
  const int bcol = wg & 15;  // 0..15

  // ---- staging descriptors ----
  // A halves: i in {0,1} -> rows 0..127 (Ah0); {2,3} -> rows 128..255 (Ah1)
  const unsigned short* srcA[4];
  unsigned int dA[4];
#pragma unroll
  for (int i = 0; i < 4; ++i) {
    int s = i * 512 + tid;
    int r = s >> 3, sch = s & 7;
    int ch = sch ^ (r & 7);
    srcA[i] = hx + (size_t)(brow * 256 + r) * KDIM + ch * 8;
    dA[i] = s * 8;
  }
  // B halves: g in {0,1} -> gates 0,1 (Bh0); {2,3} -> gates 2,3 (Bh1)
  const unsigned short* srcB[4];
  unsigned int dB[4];
  {
    int r = tid >> 3, sch = tid & 7;
    int ch = sch ^ (r & 7);
#pragma unroll
    for (int g = 0; g < 4; ++g) {
      srcB[g] = wtb + (size_t)g * 1024 * 2048 + (size_t)(bcol * 64 + r) * KDIM + ch * 8;
      dB[g] = g * 4096 + tid * 8;
    }
  }

  // ---- fragment LDS element offsets ----
  unsigned int aoff[4][2], boff[2][2];
#pragma unroll
  for (int m = 0; m < 4; ++m) {
    int row = wr * 64 + m * 16 + ll;
#pragma unroll
    for (int ks = 0; ks < 2; ++ks) {
      int ch = (ks * 4 + lg) ^ (row & 7);
      aoff[m][ks] = row * 64 + ch * 8;
    }
  }
#pragma unroll
  for (int n = 0; n < 2; ++n) {
    int row = wc * 32 + n * 16 + ll;
#pragma unroll
    for (int ks = 0; ks < 2; ++ks) {
      int ch = (ks * 4 + lg) ^ (row & 7);
      boff[n][ks] = row * 64 + ch * 8;
    }
  }

  f32x4 acc[4][4][2];
#pragma unroll
  for (int g = 0; g < 4; ++g)
#pragma unroll
    for (int m = 0; m < 4; ++m)
#pragma unroll
      for (int n = 0; n < 2; ++n)
        acc[g][m][n] = (f32x4)(0.0f);

  // ---- prologue: stage tile 0 into buf0 (half order Bh0,Ah0,Ah1,Bh1), drain once ----
  gload_lds16(srcB[0], &lB[0][dB[0]]);
  gload_lds16(srcB[1], &lB[0][dB[1]]);
  gload_lds16(srcA[0], &lA[0][dA[0]]);
  gload_lds16(srcA[1], &lA[0][dA[1]]);
  gload_lds16(srcA[2], &lA[0][dA[2]]);
  gload_lds16(srcA[3], &lA[0][dA[3]]);
  gload_lds16(srcB[2], &lB[0][dB[2]]);
  gload_lds16(srcB[3], &lB[0][dB[3]]);
#pragma unroll
  for (int i = 0; i < 4; ++i) { srcA[i] += BK; srcB[i] += BK; }
  VMC(0);
  BAR;

  // ---- main loop: tiles 0..NKT-2; tile t stages tile t+1 into the OTHER buffer ----
  for (int t = 0; t < NKT - 1; ++t) {
    const int P = t & 1;
    const unsigned short* Ab = &lA[P][0];
    const unsigned short* Bb = &lB[P][0];
    unsigned short* An = &lA[P ^ 1][0];
    unsigned short* Bn = &lB[P ^ 1][0];

    bf16x8 aF[4][2];
    bf16x8 bF[2][2];

    // ph0 (gate 0): read aF + bF0; stage Bh0(t+1)
    READ_AF()
    READ_BF(0)
    gload_lds16(srcB[0], Bn + dB[0]);
    gload_lds16(srcB[1], Bn + dB[1]);
    BAR;
    LGKM0;
    MFMA_GATE(0)
    BAR;

    // ph1 (gate 1): read bF1; stage Ah0(t+1); vmcnt(4) retires Bh1(this tile)
    READ_BF(1)
    gload_lds16(srcA[0], An + dA[0]);
    gload_lds16(srcA[1], An + dA[1]);
    BAR;
    LGKM0;
    MFMA_GATE(1)
    VMC(4);
    BAR;

    // ph2 (gate 2): read bF2; stage Ah1(t+1)
    READ_BF(2)
    gload_lds16(srcA[2], An + dA[2]);
    gload_lds16(srcA[3], An + dA[3]);
    BAR;
    LGKM0;
    MFMA_GATE(2)
    BAR;

    // ph3 (gate 3): read bF3; stage Bh1(t+1); vmcnt(2) retires Bh0,Ah0,Ah1(t+1)
    READ_BF(3)
    gload_lds16(srcB[2], Bn + dB[2]);
    gload_lds16(srcB[3], Bn + dB[3]);
    BAR;
    LGKM0;
    MFMA_GATE(3)
    VMC(2);
    BAR;

#pragma unroll
    for (int i = 0; i < 4; ++i) { srcA[i] += BK; srcB[i] += BK; }
  }

  // ---- peeled last tile (no staging; progressive drain) ----
  {
    const int P = (NKT - 1) & 1;
    const unsigned short* Ab = &lA[P][0];
    const unsigned short* Bb = &lB[P][0];

    bf16x8 aF[4][2];
    bf16x8 bF[2][2];

    READ_AF()
    READ_BF(0)
    BAR;
    LGKM0;
    MFMA_GATE(0)
    BAR;

    READ_BF(1)
    BAR;
    LGKM0;
    MFMA_GATE(1)
    VMC(0);  // retire Bh1(last)
    BAR;

    READ_BF(2)
    BAR;
    LGKM0;
    MFMA_GATE(2)
    BAR;

    READ_BF(3)
    BAR;
    LGKM0;
    MFMA_GATE(3)
  }

  // ---- epilogue: gates + cell update, store h_new (coalesced) ----
  const int row0 = brow * 256 + wr * 64;
  const int col0 = bcol * 64 + wc * 32;
  float bv[4][2];
#pragma unroll
  for (int n = 0; n < 2; ++n) {
    int col = col0 + n * 16 + ll;
    bv[0][n] = bias_f[col];
    bv[1][n] = bias_i[col];
    bv[2][n] = bias_s[col];
    bv[3][n] = bias_p[col];
  }
#pragma unroll
  for (int m = 0; m < 4; ++m)
#pragma unroll
    for (int n = 0; n < 2; ++n)
#pragma unroll
      for (int j = 0; j < 4; ++j) {
        int row = row0 + m * 16 + lg * 4 + j;
        int col = col0 + n * 16 + ll;
        float zf = acc[0][m][n][j] + bv[0][n];
        float zi = acc[1][m][n][j] + bv[1][n];
        float zs = acc[2][m][n][j] + bv[2][n];
        float zp = acc[3][m][n][j] + bv[3][n];
        float fg = sigm(zf);
        float ig = sigm(zi);
        float sg = sigm(zs);
        float pg = tanh_fast(zp);
        float cn = c_in[(size_t)row * 1024 + col] * fg + ig * pg;
        out[(size_t)row * 1024 + col] = tanh_fast(cn) * sg;
      }
}

extern "C" void kernel_launch(void* const* d_in, const int* in_sizes, int n_in,
                              void* d_out, int out_size, void* d_ws, size_t ws_size,
                              hipStream_t stream) {
  const float* x  = (const float*)d_in[0];
  const float* h  = (const float*)d_in[1];
  const float* c  = (const float*)d_in[2];
  const float* Wf = (const float*)d_in[3];
  const float* bf = (const float*)d_in[4];
  const float* Wi = (const float*)d_in[5];
  const float* bi = (const float*)d_in[6];
  const float* Ws = (const float*)d_in[7];
  const float* bs = (const float*)d_in[8];
  const float* Wp = (const float*)d_in[9];
  const float* bp = (const float*)d_in[10];
  float* out = (float*)d_out;

  unsigned short* ws = (unsigned short*)d_ws;
  unsigned short* hx  = ws;                        // 4096*2048 bf16 = 16 MB
  unsigned short* wtb = ws + (size_t)4096 * 2048;  // 4*1024*2048 bf16 = 16 MB

  pack_hx_kernel<<<(4096 * 2048 / 4) / 256, 256, 0, stream>>>(x, h, hx);

  dim3 tb(32, 8);
  dim3 tg(1024 / 32, 2048 / 32, 4);
  transpose_w4_kernel<<<tg, tb, 0, stream>>>(Wf, Wi, Ws, Wp, wtb);

  lstm_fused_kernel<<<256, 512, 0, stream>>>(hx, wtb, bf, bi, bs, bp, c, out);
}